// Round 3
// baseline (346.691 us; speedup 1.0000x reference)
//
#include <hip/hip_runtime.h>
#include <hip/hip_bf16.h>

#define NB 4
#define CC 512
#define CK 64
#define NN 4096

typedef unsigned short u16;
typedef __attribute__((ext_vector_type(8))) __bf16 bf16x8;
typedef __attribute__((ext_vector_type(4))) float f32x4;
typedef __attribute__((ext_vector_type(4))) unsigned int u32x4;
typedef __attribute__((ext_vector_type(8))) unsigned short u16x8;
typedef __attribute__((ext_vector_type(4))) unsigned short u16x4;

__device__ __forceinline__ u16 f2b(float f) {
  union { float f; unsigned u; } x; x.f = f;
  unsigned r = x.u + 0x7fffu + ((x.u >> 16) & 1u);
  return (u16)(r >> 16);
}
__device__ __forceinline__ float b2f(u16 u) {
  union { unsigned u; float f; } x; x.u = ((unsigned)u) << 16; return x.f;
}
__device__ __forceinline__ u16 cvt_bf16(float f) {
  union { __bf16 h; u16 u; } c; c.h = (__bf16)f; return c.u;
}

#define MFMA16(a, b, c) __builtin_amdgcn_mfma_f32_16x16x32_bf16((a), (b), (c), 0, 0, 0)

// ---------------------------------------------------------------------------
// proj_qk: Q/K projections with hi/lo bf16 decomposition (~fp32 accuracy).
// Q additionally pre-scaled by log2(e) so attn softmax can use native exp2.
// grid (N/64, 2, B), block 256 (4 waves, each 32x32 via 2x2 16x16 frags)
// ---------------------------------------------------------------------------
__global__ __launch_bounds__(256) void proj_qk(
    const float* __restrict__ x,
    const float* __restrict__ wb, const float* __restrict__ bb,
    const float* __restrict__ wc, const float* __restrict__ bc,
    u16* __restrict__ Qhi, u16* __restrict__ Qlo,
    u16* __restrict__ Khi, u16* __restrict__ Klo)
{
  const int tid = threadIdx.x;
  const int n0 = blockIdx.x * 64;
  const int which = blockIdx.y;
  const int b = blockIdx.z;
  const float* w   = which ? wc : wb;
  const float* bia = which ? bc : bb;
  u16* oh = which ? Khi : Qhi;
  u16* ol = which ? Klo : Qlo;
  const float qsc = which ? 1.0f : 1.44269504088896340736f;  // log2(e) on Q

  __shared__ u16 Wh[64][40], Wl[64][40], Xh[64][40], Xl[64][40];

  const int lane = tid & 63, wid = tid >> 6;
  const int wr = wid >> 1, wn = wid & 1;
  const int l15 = lane & 15, lk = (lane >> 4) * 8;

  f32x4 acc[2][2] = {};

  for (int kk = 0; kk < CC; kk += 32) {
    { // stage W tile (64 rows x 32 c), split hi/lo
      const int row = tid >> 2, c0 = (tid & 3) * 8;
      const float* src = w + (size_t)row * CC + kk + c0;
#pragma unroll
      for (int i = 0; i < 8; ++i) {
        float v = src[i];
        u16 h = f2b(v);
        Wh[row][c0 + i] = h;
        Wl[row][c0 + i] = f2b(v - b2f(h));
      }
    }
    { // stage X^T tile (64 n x 32 c), split hi/lo
      const int cc2 = tid >> 3, j0 = (tid & 7) * 8;
      const float* src = x + ((size_t)b * CC + kk + cc2) * NN + n0 + j0;
#pragma unroll
      for (int i = 0; i < 8; ++i) {
        float v = src[i];
        u16 h = f2b(v);
        Xh[j0 + i][cc2] = h;
        Xl[j0 + i][cc2] = f2b(v - b2f(h));
      }
    }
    __syncthreads();
#pragma unroll
    for (int fi = 0; fi < 2; ++fi) {
      const int ar = wr * 32 + fi * 16 + l15;
      bf16x8 ah = *(const bf16x8*)&Wh[ar][lk];
      bf16x8 al = *(const bf16x8*)&Wl[ar][lk];
#pragma unroll
      for (int fj = 0; fj < 2; ++fj) {
        const int br = wn * 32 + fj * 16 + l15;
        bf16x8 bh = *(const bf16x8*)&Xh[br][lk];
        bf16x8 bl = *(const bf16x8*)&Xl[br][lk];
        acc[fi][fj] = MFMA16(ah, bh, acc[fi][fj]);
        acc[fi][fj] = MFMA16(ah, bl, acc[fi][fj]);
        acc[fi][fj] = MFMA16(al, bh, acc[fi][fj]);
      }
    }
    __syncthreads();
  }

#pragma unroll
  for (int fi = 0; fi < 2; ++fi) {
    const int d0 = wr * 32 + fi * 16 + (lane >> 4) * 4;
#pragma unroll
    for (int fj = 0; fj < 2; ++fj) {
      const int n = n0 + wn * 32 + fj * 16 + l15;
      u16x4 vh, vl;
#pragma unroll
      for (int r = 0; r < 4; ++r) {
        float v = (acc[fi][fj][r] + bia[d0 + r]) * qsc;
        u16 h = f2b(v);
        vh[r] = h;
        vl[r] = f2b(v - b2f(h));
      }
      *(u16x4*)&oh[((size_t)b * NN + n) * CK + d0] = vh;
      *(u16x4*)&ol[((size_t)b * NN + n) * CK + d0] = vl;
    }
  }
}

// ---------------------------------------------------------------------------
// proj_v: feat_d projection, plain bf16. Vt[b][o][m] (m-contiguous).
// grid (N/64, C/64, B), block 256
// ---------------------------------------------------------------------------
__global__ __launch_bounds__(256) void proj_v(
    const float* __restrict__ x,
    const float* __restrict__ wd, const float* __restrict__ bd,
    u16* __restrict__ Vt)
{
  const int tid = threadIdx.x;
  const int n0 = blockIdx.x * 64;
  const int o0 = blockIdx.y * 64;
  const int b = blockIdx.z;

  __shared__ u16 Wt[64][40], Xt[64][40];
  const int lane = tid & 63, wid = tid >> 6;
  const int wr = wid >> 1, wn = wid & 1;
  const int l15 = lane & 15, lk = (lane >> 4) * 8;

  f32x4 acc[2][2] = {};
  for (int kk = 0; kk < CC; kk += 32) {
    {
      const int row = tid >> 2, c0 = (tid & 3) * 8;
      const float* src = wd + (size_t)(o0 + row) * CC + kk + c0;
#pragma unroll
      for (int i = 0; i < 8; ++i) Wt[row][c0 + i] = f2b(src[i]);
    }
    {
      const int cc2 = tid >> 3, j0 = (tid & 7) * 8;
      const float* src = x + ((size_t)b * CC + kk + cc2) * NN + n0 + j0;
#pragma unroll
      for (int i = 0; i < 8; ++i) Xt[j0 + i][cc2] = f2b(src[i]);
    }
    __syncthreads();
#pragma unroll
    for (int fi = 0; fi < 2; ++fi) {
      bf16x8 a = *(const bf16x8*)&Wt[wr * 32 + fi * 16 + l15][lk];
#pragma unroll
      for (int fj = 0; fj < 2; ++fj) {
        bf16x8 bv = *(const bf16x8*)&Xt[wn * 32 + fj * 16 + l15][lk];
        acc[fi][fj] = MFMA16(a, bv, acc[fi][fj]);
      }
    }
    __syncthreads();
  }
#pragma unroll
  for (int fi = 0; fi < 2; ++fi) {
    const int d0 = o0 + wr * 32 + fi * 16 + (lane >> 4) * 4;
#pragma unroll
    for (int fj = 0; fj < 2; ++fj) {
      const int n = n0 + wn * 32 + fj * 16 + l15;
#pragma unroll
      for (int r = 0; r < 4; ++r)
        Vt[((size_t)b * CC + d0 + r) * NN + n] = f2b(acc[fi][fj][r] + bd[d0 + r]);
    }
  }
}

// ---------------------------------------------------------------------------
// attn: flash attention, NOW q-split (not o-split): each block = 32 q-rows,
// ALL 512 o-cols (4 waves x 128 o). No duplicated QK^T or softmax work
// (chip-wide QK^T MFMA halves vs o-split). 512 blocks -> 2 blocks/CU.
//   - scores in log2 domain (Q pre-scaled by log2e) -> native exp2
//   - T13 defer-rescale: running max frozen unless tile max beats it by
//     >11.5 (=e^8); O-rescale gated behind __any(sc!=1) -> usually skipped
//   - P -> bf16 via native v_cvt (not manual round)
//   - Q frags in regs; V frags direct from global (L2); K dbuf in LDS.
// grid 512, block 256
// ---------------------------------------------------------------------------
struct alignas(16) AttnLds {
  u16 kh[2][64][64];
  u16 kl[2][64][64];
  float s[32][68];   // +4 pad: fp32 score tile
  u16 p[32][64];
  float m[32];
  float l[32];
  float sc[32];
};

__global__ __launch_bounds__(256, 2) void attn(
    const u16* __restrict__ Qhi, const u16* __restrict__ Qlo,
    const u16* __restrict__ Khi, const u16* __restrict__ Klo,
    const u16* __restrict__ Vt,
    const float* __restrict__ x, const float* __restrict__ alpha,
    float* __restrict__ out)
{
  __shared__ AttnLds L;
  const int tid = threadIdx.x;
  const int lane = tid & 63, wid = tid >> 6;   // 4 waves
  const int bid = blockIdx.x;
  // XCD-aware: b in bid bits 1-2 -> batch pinned to one XCD pair
  const int b = (bid >> 1) & 3;
  const int qt = ((bid >> 3) << 1) | (bid & 1);  // [0,128)
  const int q0 = qt * 32;
  const int l15 = lane & 15;
  const int lk8 = (lane >> 4) * 8;

  // QK^T role: wave handles score frag rows fi*16, cols {fj0, fj0+1}*16
  const int fi = wid >> 1;
  const int fj0 = (wid & 1) * 2;

  // K staging coords: each thread owns 16 u16 of one k-row
  const int srow = tid >> 2;
  const int sch  = (tid & 3) * 16;
  const int ssw0 = sch ^ ((srow & 7) << 3);
  const int ssw1 = (sch + 8) ^ ((srow & 7) << 3);

  // softmax coords: 8 threads per row, 8 elems each
  const int xrow = tid >> 3, xsub = tid & 7;
  const int xsw = (xsub * 8) ^ ((xrow & 7) << 3);

  // ---- prologue ----
  bf16x8 qah[2], qal[2];  // Q frag for rows q0 + fi*16
  {
    const size_t qg = ((size_t)b * NN + q0 + fi * 16 + l15) * CK + lk8;
    qah[0] = *(const bf16x8*)&Qhi[qg];
    qah[1] = *(const bf16x8*)&Qhi[qg + 32];
    qal[0] = *(const bf16x8*)&Qlo[qg];
    qal[1] = *(const bf16x8*)&Qlo[qg + 32];
  }
  { // K tile 0 -> LDS buffer 0 (swizzled)
    const size_t g = ((size_t)b * NN + srow) * CK + sch;
    *(u32x4*)&L.kh[0][srow][ssw0] = *(const u32x4*)&Khi[g];
    *(u32x4*)&L.kh[0][srow][ssw1] = *(const u32x4*)&Khi[g + 8];
    *(u32x4*)&L.kl[0][srow][ssw0] = *(const u32x4*)&Klo[g];
    *(u32x4*)&L.kl[0][srow][ssw1] = *(const u32x4*)&Klo[g + 8];
  }
  if (tid < 32) { L.m[tid] = -__builtin_huge_valf(); L.l[tid] = 0.f; }

  // per-wave V base: o rows = wid*128 + f_*16 + l15 (f_ in [0,8))
  const u16* vbase = Vt + ((size_t)b * CC + wid * 128 + l15) * NN + lk8;

  f32x4 accO[2][8] = {};  // [q frag][o frag]

  __syncthreads();  // K0 visible

  for (int t = 0; t < 64; ++t) {
    const int m0 = t * 64;
    const int cur = t & 1;
    const bool hasNext = (t < 63);

    // --- issue next-K global loads ---
    u32x4 kh0, kh1, kl0, kl1;
    if (hasNext) {
      const size_t g = ((size_t)b * NN + m0 + 64 + srow) * CK + sch;
      kh0 = *(const u32x4*)&Khi[g];
      kh1 = *(const u32x4*)&Khi[g + 8];
      kl0 = *(const u32x4*)&Klo[g];
      kl1 = *(const u32x4*)&Klo[g + 8];
    }
    // --- issue first half of V loads (ks=0) ---
    bf16x8 vr0[8], vr1[8];
#pragma unroll
    for (int f_ = 0; f_ < 8; ++f_)
      vr0[f_] = *(const bf16x8*)(vbase + (size_t)f_ * 16 * NN + m0);

    // --- QK^T: this wave's 2 score frags, hi/lo = 3 MFMAs each ---
    __builtin_amdgcn_s_setprio(1);
#pragma unroll
    for (int f2 = 0; f2 < 2; ++f2) {
      const int fj = fj0 + f2;
      f32x4 s = {};
#pragma unroll
      for (int ks = 0; ks < 2; ++ks) {
        const int k = ks * 32 + lk8;
        const int br = fj * 16 + l15;
        bf16x8 bh = *(const bf16x8*)&L.kh[cur][br][k ^ ((br & 7) << 3)];
        bf16x8 bl = *(const bf16x8*)&L.kl[cur][br][k ^ ((br & 7) << 3)];
        s = MFMA16(qah[ks], bh, s);
        s = MFMA16(qah[ks], bl, s);
        s = MFMA16(qal[ks], bh, s);
      }
      const int r0 = fi * 16 + (lane >> 4) * 4, c0 = fj * 16 + l15;
#pragma unroll
      for (int r = 0; r < 4; ++r) L.s[r0 + r][c0] = s[r];
    }
    __builtin_amdgcn_s_setprio(0);
    // --- issue second half of V loads (ks=1) ---
#pragma unroll
    for (int f_ = 0; f_ < 8; ++f_)
      vr1[f_] = *(const bf16x8*)(vbase + (size_t)f_ * 16 * NN + m0 + 32);

    __syncthreads();  // barrier A: s visible; prev-iter p reads complete

    // --- write next K tile into the other buffer ---
    if (hasNext) {
      *(u32x4*)&L.kh[cur ^ 1][srow][ssw0] = kh0;
      *(u32x4*)&L.kh[cur ^ 1][srow][ssw1] = kh1;
      *(u32x4*)&L.kl[cur ^ 1][srow][ssw0] = kl0;
      *(u32x4*)&L.kl[cur ^ 1][srow][ssw1] = kl1;
    }
    // --- online softmax (log2 domain), defer-max: 8 threads/row ---
    {
      const float* sr = &L.s[xrow][xsub * 8];
      f32x4 a0 = *(const f32x4*)&sr[0];
      f32x4 a1 = *(const f32x4*)&sr[4];
      float mx = fmaxf(fmaxf(fmaxf(a0[0], a0[1]), fmaxf(a0[2], a0[3])),
                       fmaxf(fmaxf(a1[0], a1[1]), fmaxf(a1[2], a1[3])));
      mx = fmaxf(mx, __shfl_xor(mx, 1));
      mx = fmaxf(mx, __shfl_xor(mx, 2));
      mx = fmaxf(mx, __shfl_xor(mx, 4));
      const float mOld = L.m[xrow];
      const bool grow = (mx > mOld + 11.5f);  // e^8 in log2 domain
      const float mNew = grow ? mx : mOld;
      float pv[8], sum = 0.f;
#pragma unroll
      for (int j = 0; j < 4; ++j) { pv[j] = exp2f(a0[j] - mNew); sum += pv[j]; }
#pragma unroll
      for (int j = 0; j < 4; ++j) { pv[4 + j] = exp2f(a1[j] - mNew); sum += pv[4 + j]; }
      sum += __shfl_xor(sum, 1);
      sum += __shfl_xor(sum, 2);
      sum += __shfl_xor(sum, 4);
      const float scf = grow ? exp2f(mOld - mNew) : 1.0f;
      if (xsub == 0) {
        if (grow) L.m[xrow] = mNew;
        L.l[xrow] = L.l[xrow] * scf + sum;
        L.sc[xrow] = scf;
      }
      u16x8 pb;
#pragma unroll
      for (int j = 0; j < 8; ++j) pb[j] = cvt_bf16(pv[j]);
      *(u16x8*)&L.p[xrow][xsw] = pb;
    }
    __syncthreads();  // barrier B: p + K[t+1] + m/l/sc visible

    // --- gated rescale (usually skipped after warm-up) ---
    {
      float scv[8];
      bool need = false;
#pragma unroll
      for (int f_ = 0; f_ < 2; ++f_)
#pragma unroll
        for (int r = 0; r < 4; ++r) {
          float s_ = L.sc[f_ * 16 + (lane >> 4) * 4 + r];
          scv[f_ * 4 + r] = s_;
          need |= (s_ != 1.0f);
        }
      if (__any(need)) {
#pragma unroll
        for (int f_ = 0; f_ < 2; ++f_)
#pragma unroll
          for (int fj = 0; fj < 8; ++fj)
#pragma unroll
            for (int r = 0; r < 4; ++r)
              accO[f_][fj][r] *= scv[f_ * 4 + r];
      }
    }
    // --- PV: 2 q-frags x 8 o-frags x 2 ks ---
    __builtin_amdgcn_s_setprio(1);
    {
      const int k0 = lk8;
      bf16x8 a0 = *(const bf16x8*)&L.p[l15][k0 ^ ((l15 & 7) << 3)];
      bf16x8 a1 = *(const bf16x8*)&L.p[16 + l15][k0 ^ ((l15 & 7) << 3)];
#pragma unroll
      for (int fj = 0; fj < 8; ++fj) {
        accO[0][fj] = MFMA16(a0, vr0[fj], accO[0][fj]);
        accO[1][fj] = MFMA16(a1, vr0[fj], accO[1][fj]);
      }
      const int k1 = 32 + lk8;
      bf16x8 a2 = *(const bf16x8*)&L.p[l15][k1 ^ ((l15 & 7) << 3)];
      bf16x8 a3 = *(const bf16x8*)&L.p[16 + l15][k1 ^ ((l15 & 7) << 3)];
#pragma unroll
      for (int fj = 0; fj < 8; ++fj) {
        accO[0][fj] = MFMA16(a2, vr1[fj], accO[0][fj]);
        accO[1][fj] = MFMA16(a3, vr1[fj], accO[1][fj]);
      }
    }
    __builtin_amdgcn_s_setprio(0);
  }
  __syncthreads();
  // epilogue: out = alpha * (O / l) + x
  const float al = alpha[0];
#pragma unroll
  for (int f_ = 0; f_ < 2; ++f_) {
    const int r0 = f_ * 16 + (lane >> 4) * 4;
    const float rl0 = 1.f / L.l[r0],     rl1 = 1.f / L.l[r0 + 1];
    const float rl2 = 1.f / L.l[r0 + 2], rl3 = 1.f / L.l[r0 + 3];
    const int n_ = q0 + r0;
#pragma unroll
    for (int fj = 0; fj < 8; ++fj) {
      const int c_ = wid * 128 + fj * 16 + l15;
      const size_t g = ((size_t)b * CC + c_) * NN + n_;
      f32x4 xv = *(const f32x4*)&x[g];
      f32x4 ov;
      ov[0] = fmaf(al, accO[f_][fj][0] * rl0, xv[0]);
      ov[1] = fmaf(al, accO[f_][fj][1] * rl1, xv[1]);
      ov[2] = fmaf(al, accO[f_][fj][2] * rl2, xv[2]);
      ov[3] = fmaf(al, accO[f_][fj][3] * rl3, xv[3]);
      *(f32x4*)&out[g] = ov;
    }
  }
}

extern "C" void kernel_launch(void* const* d_in, const int* in_sizes, int n_in,
                              void* d_out, int out_size, void* d_ws, size_t ws_size,
                              hipStream_t stream) {
  const float* x     = (const float*)d_in[0];
  const float* wb    = (const float*)d_in[1];
  const float* bb    = (const float*)d_in[2];
  const float* wc    = (const float*)d_in[3];
  const float* bc    = (const float*)d_in[4];
  const float* wd    = (const float*)d_in[5];
  const float* bd    = (const float*)d_in[6];
  const float* alpha = (const float*)d_in[7];
  float* out = (float*)d_out;

  // workspace: Qhi|Qlo|Khi|Klo (2MB each) + Vt (16MB) = 24MB
  u16* Qhi = (u16*)d_ws;
  u16* Qlo = Qhi + (size_t)NB * NN * CK;
  u16* Khi = Qlo + (size_t)NB * NN * CK;
  u16* Klo = Khi + (size_t)NB * NN * CK;
  u16* Vt  = Klo + (size_t)NB * NN * CK;

  proj_qk<<<dim3(NN / 64, 2, NB), 256, 0, stream>>>(x, wb, bb, wc, bc, Qhi, Qlo, Khi, Klo);
  proj_v<<<dim3(NN / 64, CC / 64, NB), 256, 0, stream>>>(x, wd, bd, Vt);
  attn<<<dim3(512), 256, 0, stream>>>(Qhi, Qlo, Khi, Klo, Vt, x, alpha, out);
}

// Round 4
// 242.909 us; speedup vs baseline: 1.4272x; 1.4272x over previous
//
#include <hip/hip_runtime.h>
#include <hip/hip_bf16.h>

#define NB 4
#define CC 512
#define CK 64
#define NN 4096

typedef unsigned short u16;
typedef __attribute__((ext_vector_type(8))) __bf16 bf16x8;
typedef __attribute__((ext_vector_type(4))) float f32x4;
typedef __attribute__((ext_vector_type(4))) unsigned int u32x4;
typedef __attribute__((ext_vector_type(8))) unsigned short u16x8;
typedef __attribute__((ext_vector_type(4))) unsigned short u16x4;

__device__ __forceinline__ u16 f2b(float f) {
  union { float f; unsigned u; } x; x.f = f;
  unsigned r = x.u + 0x7fffu + ((x.u >> 16) & 1u);
  return (u16)(r >> 16);
}
__device__ __forceinline__ float b2f(u16 u) {
  union { unsigned u; float f; } x; x.u = ((unsigned)u) << 16; return x.f;
}
__device__ __forceinline__ u16 cvt_bf16(float f) {
  union { __bf16 h; u16 u; } c; c.h = (__bf16)f; return c.u;
}

#define MFMA16(a, b, c) __builtin_amdgcn_mfma_f32_16x16x32_bf16((a), (b), (c), 0, 0, 0)

// ---------------------------------------------------------------------------
// proj_qk: Q/K projections with hi/lo bf16 decomposition (~fp32 accuracy).
// Q additionally pre-scaled by log2(e) so attn softmax can use native exp2.
// grid (N/64, 2, B), block 256 (4 waves, each 32x32 via 2x2 16x16 frags)
// ---------------------------------------------------------------------------
__global__ __launch_bounds__(256) void proj_qk(
    const float* __restrict__ x,
    const float* __restrict__ wb, const float* __restrict__ bb,
    const float* __restrict__ wc, const float* __restrict__ bc,
    u16* __restrict__ Qhi, u16* __restrict__ Qlo,
    u16* __restrict__ Khi, u16* __restrict__ Klo)
{
  const int tid = threadIdx.x;
  const int n0 = blockIdx.x * 64;
  const int which = blockIdx.y;
  const int b = blockIdx.z;
  const float* w   = which ? wc : wb;
  const float* bia = which ? bc : bb;
  u16* oh = which ? Khi : Qhi;
  u16* ol = which ? Klo : Qlo;
  const float qsc = which ? 1.0f : 1.44269504088896340736f;  // log2(e) on Q

  __shared__ u16 Wh[64][40], Wl[64][40], Xh[64][40], Xl[64][40];

  const int lane = tid & 63, wid = tid >> 6;
  const int wr = wid >> 1, wn = wid & 1;
  const int l15 = lane & 15, lk = (lane >> 4) * 8;

  f32x4 acc[2][2] = {};

  for (int kk = 0; kk < CC; kk += 32) {
    { // stage W tile (64 rows x 32 c), split hi/lo
      const int row = tid >> 2, c0 = (tid & 3) * 8;
      const float* src = w + (size_t)row * CC + kk + c0;
#pragma unroll
      for (int i = 0; i < 8; ++i) {
        float v = src[i];
        u16 h = f2b(v);
        Wh[row][c0 + i] = h;
        Wl[row][c0 + i] = f2b(v - b2f(h));
      }
    }
    { // stage X^T tile (64 n x 32 c), split hi/lo
      const int cc2 = tid >> 3, j0 = (tid & 7) * 8;
      const float* src = x + ((size_t)b * CC + kk + cc2) * NN + n0 + j0;
#pragma unroll
      for (int i = 0; i < 8; ++i) {
        float v = src[i];
        u16 h = f2b(v);
        Xh[j0 + i][cc2] = h;
        Xl[j0 + i][cc2] = f2b(v - b2f(h));
      }
    }
    __syncthreads();
#pragma unroll
    for (int fi = 0; fi < 2; ++fi) {
      const int ar = wr * 32 + fi * 16 + l15;
      bf16x8 ah = *(const bf16x8*)&Wh[ar][lk];
      bf16x8 al = *(const bf16x8*)&Wl[ar][lk];
#pragma unroll
      for (int fj = 0; fj < 2; ++fj) {
        const int br = wn * 32 + fj * 16 + l15;
        bf16x8 bh = *(const bf16x8*)&Xh[br][lk];
        bf16x8 bl = *(const bf16x8*)&Xl[br][lk];
        acc[fi][fj] = MFMA16(ah, bh, acc[fi][fj]);
        acc[fi][fj] = MFMA16(ah, bl, acc[fi][fj]);
        acc[fi][fj] = MFMA16(al, bh, acc[fi][fj]);
      }
    }
    __syncthreads();
  }

#pragma unroll
  for (int fi = 0; fi < 2; ++fi) {
    const int d0 = wr * 32 + fi * 16 + (lane >> 4) * 4;
#pragma unroll
    for (int fj = 0; fj < 2; ++fj) {
      const int n = n0 + wn * 32 + fj * 16 + l15;
      u16x4 vh, vl;
#pragma unroll
      for (int r = 0; r < 4; ++r) {
        float v = (acc[fi][fj][r] + bia[d0 + r]) * qsc;
        u16 h = f2b(v);
        vh[r] = h;
        vl[r] = f2b(v - b2f(h));
      }
      *(u16x4*)&oh[((size_t)b * NN + n) * CK + d0] = vh;
      *(u16x4*)&ol[((size_t)b * NN + n) * CK + d0] = vl;
    }
  }
}

// ---------------------------------------------------------------------------
// proj_v: feat_d projection, plain bf16. Vt[b][o][m] (m-contiguous).
// grid (N/64, C/64, B), block 256
// ---------------------------------------------------------------------------
__global__ __launch_bounds__(256) void proj_v(
    const float* __restrict__ x,
    const float* __restrict__ wd, const float* __restrict__ bd,
    u16* __restrict__ Vt)
{
  const int tid = threadIdx.x;
  const int n0 = blockIdx.x * 64;
  const int o0 = blockIdx.y * 64;
  const int b = blockIdx.z;

  __shared__ u16 Wt[64][40], Xt[64][40];
  const int lane = tid & 63, wid = tid >> 6;
  const int wr = wid >> 1, wn = wid & 1;
  const int l15 = lane & 15, lk = (lane >> 4) * 8;

  f32x4 acc[2][2] = {};
  for (int kk = 0; kk < CC; kk += 32) {
    {
      const int row = tid >> 2, c0 = (tid & 3) * 8;
      const float* src = wd + (size_t)(o0 + row) * CC + kk + c0;
#pragma unroll
      for (int i = 0; i < 8; ++i) Wt[row][c0 + i] = f2b(src[i]);
    }
    {
      const int cc2 = tid >> 3, j0 = (tid & 7) * 8;
      const float* src = x + ((size_t)b * CC + kk + cc2) * NN + n0 + j0;
#pragma unroll
      for (int i = 0; i < 8; ++i) Xt[j0 + i][cc2] = f2b(src[i]);
    }
    __syncthreads();
#pragma unroll
    for (int fi = 0; fi < 2; ++fi) {
      bf16x8 a = *(const bf16x8*)&Wt[wr * 32 + fi * 16 + l15][lk];
#pragma unroll
      for (int fj = 0; fj < 2; ++fj) {
        bf16x8 bv = *(const bf16x8*)&Xt[wn * 32 + fj * 16 + l15][lk];
        acc[fi][fj] = MFMA16(a, bv, acc[fi][fj]);
      }
    }
    __syncthreads();
  }
#pragma unroll
  for (int fi = 0; fi < 2; ++fi) {
    const int d0 = o0 + wr * 32 + fi * 16 + (lane >> 4) * 4;
#pragma unroll
    for (int fj = 0; fj < 2; ++fj) {
      const int n = n0 + wn * 32 + fj * 16 + l15;
#pragma unroll
      for (int r = 0; r < 4; ++r)
        Vt[((size_t)b * CC + d0 + r) * NN + n] = f2b(acc[fi][fj][r] + bd[d0 + r]);
    }
  }
}

// ---------------------------------------------------------------------------
// attn: flash attention, round-2 structure (o-split: 2 blocks per (b,q-tile),
// each 256 thr = 4 waves, 64 q-rows x 256 o-cols) + VALU diet:
//   - scores in log2 domain (Q pre-scaled by log2e) -> native exp2
//   - T13 defer-max: running max frozen unless tile max beats it by >11.5
//     (= e^8); O-rescale gated behind __any(sc != 1) -> usually skipped
//   - P -> bf16 via native v_cvt (not manual rounding)
//   - SINGLE K buffer (2-barrier structure already serializes writes/reads;
//     saves 16 KB LDS)
//   - Q frags in regs; V frags direct from global (L2); async K stage split.
// grid 512, block 256, 2 blocks/CU
// ---------------------------------------------------------------------------
struct alignas(16) AttnLds {
  u16 kh[64][64];
  u16 kl[64][64];
  float s[64][68];   // +4 pad: fp32 score tile
  u16 p[64][64];
  float m[64];
  float l[64];
  float sc[64];
};

__global__ __launch_bounds__(256, 2) void attn(
    const u16* __restrict__ Qhi, const u16* __restrict__ Qlo,
    const u16* __restrict__ Khi, const u16* __restrict__ Klo,
    const u16* __restrict__ Vt,
    const float* __restrict__ x, const float* __restrict__ alpha,
    float* __restrict__ out)
{
  __shared__ AttnLds L;
  const int tid = threadIdx.x;
  const int lane = tid & 63, wid = tid >> 6;   // 4 waves
  const int bid = blockIdx.x;
  // XCD-aware remap: b uses bid bits 1-2 -> batch pinned to one XCD pair
  const int b = (bid >> 1) & 3;
  const int qt = bid >> 3;        // [0,64)
  const int ohalf = bid & 1;      // o-half: columns [ohalf*256, +256)
  const int q0 = qt * 64;
  const int l15 = lane & 15;
  const int lk8 = (lane >> 4) * 8;

  // staging/softmax coords: 4 threads per row, 16 u16 (two u32x4) each
  const int srow = tid >> 2;
  const int sch  = (tid & 3) * 16;
  const int ssw0 = sch ^ ((srow & 7) << 3);
  const int ssw1 = (sch + 8) ^ ((srow & 7) << 3);

  // ---- prologue ----
  // Q fragments (iteration-invariant): wave wid owns score rows wid*16..+15
  bf16x8 qah[2], qal[2];
  {
    const size_t qg = ((size_t)b * NN + q0 + wid * 16 + l15) * CK + lk8;
    qah[0] = *(const bf16x8*)&Qhi[qg];
    qah[1] = *(const bf16x8*)&Qhi[qg + 32];
    qal[0] = *(const bf16x8*)&Qlo[qg];
    qal[1] = *(const bf16x8*)&Qlo[qg + 32];
  }
  { // K tile 0 -> LDS (swizzled)
    const size_t g = ((size_t)b * NN + srow) * CK + sch;
    *(u32x4*)&L.kh[srow][ssw0] = *(const u32x4*)&Khi[g];
    *(u32x4*)&L.kh[srow][ssw1] = *(const u32x4*)&Khi[g + 8];
    *(u32x4*)&L.kl[srow][ssw0] = *(const u32x4*)&Klo[g];
    *(u32x4*)&L.kl[srow][ssw1] = *(const u32x4*)&Klo[g + 8];
  }
  if (tid < 64) { L.m[tid] = -__builtin_huge_valf(); L.l[tid] = 0.f; }

  // per-wave V base: rows o = ohalf*256 + wid*64 + fj*16 + l15
  const u16* vbase = Vt + ((size_t)b * CC + ohalf * 256 + wid * 64 + l15) * NN + lk8;

  f32x4 accO[4][4] = {};  // [q frag][o frag]

  __syncthreads();  // K0 visible

  for (int t = 0; t < 64; ++t) {
    const int m0 = t * 64;
    const bool hasNext = (t < 63);

    // --- issue next-K global loads (held in regs until after barrier A) ---
    u32x4 kh0, kh1, kl0, kl1;
    if (hasNext) {
      const size_t g = ((size_t)b * NN + m0 + 64 + srow) * CK + sch;
      kh0 = *(const u32x4*)&Khi[g];
      kh1 = *(const u32x4*)&Khi[g + 8];
      kl0 = *(const u32x4*)&Klo[g];
      kl1 = *(const u32x4*)&Klo[g + 8];
    }
    // --- issue V fragment loads for THIS tile (consumed in PV) ---
    bf16x8 vr[2][4];  // [ks][fj]
#pragma unroll
    for (int f_ = 0; f_ < 4; ++f_)
#pragma unroll
      for (int ks = 0; ks < 2; ++ks)
        vr[ks][f_] = *(const bf16x8*)(vbase + (size_t)f_ * 16 * NN + m0 + ks * 32);

    // --- QK^T: wave wid does score rows wid*16, all 4 col frags ---
    __builtin_amdgcn_s_setprio(1);
#pragma unroll
    for (int fj = 0; fj < 4; ++fj) {
      f32x4 s = {};
#pragma unroll
      for (int ks = 0; ks < 2; ++ks) {
        const int k = ks * 32 + lk8;
        const int br = fj * 16 + l15;
        bf16x8 bh = *(const bf16x8*)&L.kh[br][k ^ ((br & 7) << 3)];
        bf16x8 bl = *(const bf16x8*)&L.kl[br][k ^ ((br & 7) << 3)];
        s = MFMA16(qah[ks], bh, s);
        s = MFMA16(qah[ks], bl, s);
        s = MFMA16(qal[ks], bh, s);
      }
      const int r0 = wid * 16 + (lane >> 4) * 4, c0 = fj * 16 + l15;
#pragma unroll
      for (int r = 0; r < 4; ++r) L.s[r0 + r][c0] = s[r];
    }
    __builtin_amdgcn_s_setprio(0);
    __syncthreads();  // barrier A: s visible; QK^T K-reads + prev p-reads done

    // --- write next K tile (single buffer: QK^T(t) done, next read after B) ---
    if (hasNext) {
      *(u32x4*)&L.kh[srow][ssw0] = kh0;
      *(u32x4*)&L.kh[srow][ssw1] = kh1;
      *(u32x4*)&L.kl[srow][ssw0] = kl0;
      *(u32x4*)&L.kl[srow][ssw1] = kl1;
    }
    // --- online softmax (log2 domain), defer-max: 4 threads/row ---
    {
      const int row = srow, sub = tid & 3;
      const float* sr = &L.s[row][sch];
      f32x4 a0 = *(const f32x4*)&sr[0];
      f32x4 a1 = *(const f32x4*)&sr[4];
      f32x4 a2 = *(const f32x4*)&sr[8];
      f32x4 a3 = *(const f32x4*)&sr[12];
      float mx = fmaxf(fmaxf(fmaxf(a0[0], a0[1]), fmaxf(a0[2], a0[3])),
                       fmaxf(fmaxf(a1[0], a1[1]), fmaxf(a1[2], a1[3])));
      mx = fmaxf(mx, fmaxf(fmaxf(fmaxf(a2[0], a2[1]), fmaxf(a2[2], a2[3])),
                           fmaxf(fmaxf(a3[0], a3[1]), fmaxf(a3[2], a3[3]))));
      mx = fmaxf(mx, __shfl_xor(mx, 1));
      mx = fmaxf(mx, __shfl_xor(mx, 2));
      const float mOld = L.m[row];
      const bool grow = (mx > mOld + 11.5f);  // e^8 in log2 domain (T13)
      const float mNew = grow ? mx : mOld;
      float pv[16];
      float sum = 0.f;
#pragma unroll
      for (int j = 0; j < 4; ++j) { pv[j]      = exp2f(a0[j] - mNew); sum += pv[j]; }
#pragma unroll
      for (int j = 0; j < 4; ++j) { pv[4 + j]  = exp2f(a1[j] - mNew); sum += pv[4 + j]; }
#pragma unroll
      for (int j = 0; j < 4; ++j) { pv[8 + j]  = exp2f(a2[j] - mNew); sum += pv[8 + j]; }
#pragma unroll
      for (int j = 0; j < 4; ++j) { pv[12 + j] = exp2f(a3[j] - mNew); sum += pv[12 + j]; }
      sum += __shfl_xor(sum, 1);
      sum += __shfl_xor(sum, 2);
      const float scf = grow ? exp2f(mOld - mNew) : 1.0f;
      if (sub == 0) {
        if (grow) L.m[row] = mNew;
        L.l[row] = L.l[row] * scf + sum;
        L.sc[row] = scf;
      }
      u16x8 pb0, pb1;
#pragma unroll
      for (int j = 0; j < 8; ++j) pb0[j] = cvt_bf16(pv[j]);
#pragma unroll
      for (int j = 0; j < 8; ++j) pb1[j] = cvt_bf16(pv[8 + j]);
      *(u16x8*)&L.p[row][ssw0] = pb0;
      *(u16x8*)&L.p[row][ssw1] = pb1;
    }
    __syncthreads();  // barrier B: p + K[t+1] + m/l/sc visible

    // --- gated rescale (usually skipped after warm-up) ---
    {
      f32x4 scv[4];
      bool need = false;
#pragma unroll
      for (int f_ = 0; f_ < 4; ++f_) {
        scv[f_] = *(const f32x4*)&L.sc[f_ * 16 + (lane >> 4) * 4];
        need |= (scv[f_][0] != 1.0f) | (scv[f_][1] != 1.0f) |
                (scv[f_][2] != 1.0f) | (scv[f_][3] != 1.0f);
      }
      if (__any(need)) {
#pragma unroll
        for (int f_ = 0; f_ < 4; ++f_)
#pragma unroll
          for (int fj = 0; fj < 4; ++fj)
#pragma unroll
            for (int r = 0; r < 4; ++r)
              accO[f_][fj][r] *= scv[f_][r];
      }
    }
    // --- PV (V operands already in regs) ---
    __builtin_amdgcn_s_setprio(1);
#pragma unroll
    for (int ks = 0; ks < 2; ++ks) {
      const int k = ks * 32 + lk8;
      bf16x8 a[4];
#pragma unroll
      for (int f_ = 0; f_ < 4; ++f_) {
        const int ar = f_ * 16 + l15;
        a[f_] = *(const bf16x8*)&L.p[ar][k ^ ((ar & 7) << 3)];
      }
#pragma unroll
      for (int fj = 0; fj < 4; ++fj)
#pragma unroll
        for (int f_ = 0; f_ < 4; ++f_)
          accO[f_][fj] = MFMA16(a[f_], vr[ks][fj], accO[f_][fj]);
    }
    __builtin_amdgcn_s_setprio(0);
  }
  __syncthreads();
  // epilogue: out = alpha * (O / l) + x
  const float al = alpha[0];
#pragma unroll
  for (int f_ = 0; f_ < 4; ++f_) {
    const int r0 = f_ * 16 + (lane >> 4) * 4;
    const float rl0 = 1.f / L.l[r0],     rl1 = 1.f / L.l[r0 + 1];
    const float rl2 = 1.f / L.l[r0 + 2], rl3 = 1.f / L.l[r0 + 3];
    const int n_ = q0 + r0;
#pragma unroll
    for (int fj = 0; fj < 4; ++fj) {
      const int c_ = ohalf * 256 + wid * 64 + fj * 16 + l15;
      const size_t g = ((size_t)b * CC + c_) * NN + n_;
      f32x4 xv = *(const f32x4*)&x[g];
      f32x4 ov;
      ov[0] = fmaf(al, accO[f_][fj][0] * rl0, xv[0]);
      ov[1] = fmaf(al, accO[f_][fj][1] * rl1, xv[1]);
      ov[2] = fmaf(al, accO[f_][fj][2] * rl2, xv[2]);
      ov[3] = fmaf(al, accO[f_][fj][3] * rl3, xv[3]);
      *(f32x4*)&out[g] = ov;
    }
  }
}

extern "C" void kernel_launch(void* const* d_in, const int* in_sizes, int n_in,
                              void* d_out, int out_size, void* d_ws, size_t ws_size,
                              hipStream_t stream) {
  const float* x     = (const float*)d_in[0];
  const float* wb    = (const float*)d_in[1];
  const float* bb    = (const float*)d_in[2];
  const float* wc    = (const float*)d_in[3];
  const float* bc    = (const float*)d_in[4];
  const float* wd    = (const float*)d_in[5];
  const float* bd    = (const float*)d_in[6];
  const float* alpha = (const float*)d_in[7];
  float* out = (float*)d_out;

  // workspace: Qhi|Qlo|Khi|Klo (2MB each) + Vt (16MB) = 24MB
  u16* Qhi = (u16*)d_ws;
  u16* Qlo = Qhi + (size_t)NB * NN * CK;
  u16* Khi = Qlo + (size_t)NB * NN * CK;
  u16* Klo = Khi + (size_t)NB * NN * CK;
  u16* Vt  = Klo + (size_t)NB * NN * CK;

  proj_qk<<<dim3(NN / 64, 2, NB), 256, 0, stream>>>(x, wb, bb, wc, bc, Qhi, Qlo, Khi, Klo);
  proj_v<<<dim3(NN / 64, CC / 64, NB), 256, 0, stream>>>(x, wd, bd, Vt);
  attn<<<dim3(512), 256, 0, stream>>>(Qhi, Qlo, Khi, Klo, Vt, x, alpha, out);
}

// Round 5
// 231.323 us; speedup vs baseline: 1.4987x; 1.0501x over previous
//
#include <hip/hip_runtime.h>
#include <hip/hip_bf16.h>

#define NB 4
#define CC 512
#define CK 64
#define NN 4096

typedef unsigned short u16;
typedef __attribute__((ext_vector_type(8))) __bf16 bf16x8;
typedef __attribute__((ext_vector_type(4))) float f32x4;
typedef __attribute__((ext_vector_type(4))) unsigned int u32x4;
typedef __attribute__((ext_vector_type(8))) unsigned short u16x8;
typedef __attribute__((ext_vector_type(4))) unsigned short u16x4;

__device__ __forceinline__ u16 f2b(float f) {
  union { float f; unsigned u; } x; x.f = f;
  unsigned r = x.u + 0x7fffu + ((x.u >> 16) & 1u);
  return (u16)(r >> 16);
}
__device__ __forceinline__ float b2f(u16 u) {
  union { unsigned u; float f; } x; x.u = ((unsigned)u) << 16; return x.f;
}
__device__ __forceinline__ u16 cvt_bf16(float f) {
  union { __bf16 h; u16 u; } c; c.h = (__bf16)f; return c.u;
}
// raw v_exp_f32 (2^x): single transcendental op, no libm range-fixup
__device__ __forceinline__ float fast_exp2(float x) {
  float r;
  asm("v_exp_f32 %0, %1" : "=v"(r) : "v"(x));
  return r;
}
// barrier with LDS-only drain: global loads stay in flight across it
__device__ __forceinline__ void lds_barrier() {
  asm volatile("s_waitcnt lgkmcnt(0)" ::: "memory");
  __builtin_amdgcn_s_barrier();
}

#define MFMA16(a, b, c) __builtin_amdgcn_mfma_f32_16x16x32_bf16((a), (b), (c), 0, 0, 0)

// ---------------------------------------------------------------------------
// proj_qk: Q/K projections with hi/lo bf16 decomposition (~fp32 accuracy).
// Q additionally pre-scaled by log2(e) so attn softmax can use native exp2.
// grid (N/64, 2, B), block 256 (4 waves, each 32x32 via 2x2 16x16 frags)
// ---------------------------------------------------------------------------
__global__ __launch_bounds__(256) void proj_qk(
    const float* __restrict__ x,
    const float* __restrict__ wb, const float* __restrict__ bb,
    const float* __restrict__ wc, const float* __restrict__ bc,
    u16* __restrict__ Qhi, u16* __restrict__ Qlo,
    u16* __restrict__ Khi, u16* __restrict__ Klo)
{
  const int tid = threadIdx.x;
  const int n0 = blockIdx.x * 64;
  const int which = blockIdx.y;
  const int b = blockIdx.z;
  const float* w   = which ? wc : wb;
  const float* bia = which ? bc : bb;
  u16* oh = which ? Khi : Qhi;
  u16* ol = which ? Klo : Qlo;
  const float qsc = which ? 1.0f : 1.44269504088896340736f;  // log2(e) on Q

  __shared__ u16 Wh[64][40], Wl[64][40], Xh[64][40], Xl[64][40];

  const int lane = tid & 63, wid = tid >> 6;
  const int wr = wid >> 1, wn = wid & 1;
  const int l15 = lane & 15, lk = (lane >> 4) * 8;

  f32x4 acc[2][2] = {};

  for (int kk = 0; kk < CC; kk += 32) {
    { // stage W tile (64 rows x 32 c), split hi/lo
      const int row = tid >> 2, c0 = (tid & 3) * 8;
      const float* src = w + (size_t)row * CC + kk + c0;
#pragma unroll
      for (int i = 0; i < 8; ++i) {
        float v = src[i];
        u16 h = f2b(v);
        Wh[row][c0 + i] = h;
        Wl[row][c0 + i] = f2b(v - b2f(h));
      }
    }
    { // stage X^T tile (64 n x 32 c), split hi/lo
      const int cc2 = tid >> 3, j0 = (tid & 7) * 8;
      const float* src = x + ((size_t)b * CC + kk + cc2) * NN + n0 + j0;
#pragma unroll
      for (int i = 0; i < 8; ++i) {
        float v = src[i];
        u16 h = f2b(v);
        Xh[j0 + i][cc2] = h;
        Xl[j0 + i][cc2] = f2b(v - b2f(h));
      }
    }
    __syncthreads();
#pragma unroll
    for (int fi = 0; fi < 2; ++fi) {
      const int ar = wr * 32 + fi * 16 + l15;
      bf16x8 ah = *(const bf16x8*)&Wh[ar][lk];
      bf16x8 al = *(const bf16x8*)&Wl[ar][lk];
#pragma unroll
      for (int fj = 0; fj < 2; ++fj) {
        const int br = wn * 32 + fj * 16 + l15;
        bf16x8 bh = *(const bf16x8*)&Xh[br][lk];
        bf16x8 bl = *(const bf16x8*)&Xl[br][lk];
        acc[fi][fj] = MFMA16(ah, bh, acc[fi][fj]);
        acc[fi][fj] = MFMA16(ah, bl, acc[fi][fj]);
        acc[fi][fj] = MFMA16(al, bh, acc[fi][fj]);
      }
    }
    __syncthreads();
  }

#pragma unroll
  for (int fi = 0; fi < 2; ++fi) {
    const int d0 = wr * 32 + fi * 16 + (lane >> 4) * 4;
#pragma unroll
    for (int fj = 0; fj < 2; ++fj) {
      const int n = n0 + wn * 32 + fj * 16 + l15;
      u16x4 vh, vl;
#pragma unroll
      for (int r = 0; r < 4; ++r) {
        float v = (acc[fi][fj][r] + bia[d0 + r]) * qsc;
        u16 h = f2b(v);
        vh[r] = h;
        vl[r] = f2b(v - b2f(h));
      }
      *(u16x4*)&oh[((size_t)b * NN + n) * CK + d0] = vh;
      *(u16x4*)&ol[((size_t)b * NN + n) * CK + d0] = vl;
    }
  }
}

// ---------------------------------------------------------------------------
// proj_v: feat_d projection, plain bf16. Vt[b][o][m] (m-contiguous).
// grid (N/64, C/64, B), block 256
// ---------------------------------------------------------------------------
__global__ __launch_bounds__(256) void proj_v(
    const float* __restrict__ x,
    const float* __restrict__ wd, const float* __restrict__ bd,
    u16* __restrict__ Vt)
{
  const int tid = threadIdx.x;
  const int n0 = blockIdx.x * 64;
  const int o0 = blockIdx.y * 64;
  const int b = blockIdx.z;

  __shared__ u16 Wt[64][40], Xt[64][40];
  const int lane = tid & 63, wid = tid >> 6;
  const int wr = wid >> 1, wn = wid & 1;
  const int l15 = lane & 15, lk = (lane >> 4) * 8;

  f32x4 acc[2][2] = {};
  for (int kk = 0; kk < CC; kk += 32) {
    {
      const int row = tid >> 2, c0 = (tid & 3) * 8;
      const float* src = wd + (size_t)(o0 + row) * CC + kk + c0;
#pragma unroll
      for (int i = 0; i < 8; ++i) Wt[row][c0 + i] = f2b(src[i]);
    }
    {
      const int cc2 = tid >> 3, j0 = (tid & 7) * 8;
      const float* src = x + ((size_t)b * CC + kk + cc2) * NN + n0 + j0;
#pragma unroll
      for (int i = 0; i < 8; ++i) Xt[j0 + i][cc2] = f2b(src[i]);
    }
    __syncthreads();
#pragma unroll
    for (int fi = 0; fi < 2; ++fi) {
      bf16x8 a = *(const bf16x8*)&Wt[wr * 32 + fi * 16 + l15][lk];
#pragma unroll
      for (int fj = 0; fj < 2; ++fj) {
        bf16x8 bv = *(const bf16x8*)&Xt[wn * 32 + fj * 16 + l15][lk];
        acc[fi][fj] = MFMA16(a, bv, acc[fi][fj]);
      }
    }
    __syncthreads();
  }
#pragma unroll
  for (int fi = 0; fi < 2; ++fi) {
    const int d0 = o0 + wr * 32 + fi * 16 + (lane >> 4) * 4;
#pragma unroll
    for (int fj = 0; fj < 2; ++fj) {
      const int n = n0 + wn * 32 + fj * 16 + l15;
#pragma unroll
      for (int r = 0; r < 4; ++r)
        Vt[((size_t)b * CC + d0 + r) * NN + n] = f2b(acc[fi][fj][r] + bd[d0 + r]);
    }
  }
}

// ---------------------------------------------------------------------------
// attn: flash attention (o-split: 2 blocks per (b,q-tile), each 256 thr =
// 4 waves, 64 q-rows x 256 o-cols; 2 blocks/CU).
//   - RAW barriers with lgkmcnt-only drain in main loop: in-loop cross-wave
//     hazards are all LDS; global loads (V frags, next-K) stay in flight
//     across barriers instead of being vmcnt(0)-drained twice per iter.
//   - log2-domain softmax via raw v_exp_f32 (Q pre-scaled by log2e)
//   - T13 defer-max + gated O-rescale
//   - single K LDS buffer; Q frags in regs; V frags direct from global (L2)
// grid 512, block 256
// ---------------------------------------------------------------------------
struct alignas(16) AttnLds {
  u16 kh[64][64];
  u16 kl[64][64];
  float s[64][68];   // +4 pad: fp32 score tile
  u16 p[64][64];
  float m[64];
  float l[64];
  float sc[64];
};

__global__ __launch_bounds__(256, 2) void attn(
    const u16* __restrict__ Qhi, const u16* __restrict__ Qlo,
    const u16* __restrict__ Khi, const u16* __restrict__ Klo,
    const u16* __restrict__ Vt,
    const float* __restrict__ x, const float* __restrict__ alpha,
    float* __restrict__ out)
{
  __shared__ AttnLds L;
  const int tid = threadIdx.x;
  const int lane = tid & 63, wid = tid >> 6;   // 4 waves
  const int bid = blockIdx.x;
  // XCD-aware remap: b uses bid bits 1-2 -> batch pinned to one XCD pair
  const int b = (bid >> 1) & 3;
  const int qt = bid >> 3;        // [0,64)
  const int ohalf = bid & 1;      // o-half: columns [ohalf*256, +256)
  const int q0 = qt * 64;
  const int l15 = lane & 15;
  const int lk8 = (lane >> 4) * 8;

  // staging/softmax coords: 4 threads per row, 16 u16 (two u32x4) each
  const int srow = tid >> 2;
  const int sch  = (tid & 3) * 16;
  const int ssw0 = sch ^ ((srow & 7) << 3);
  const int ssw1 = (sch + 8) ^ ((srow & 7) << 3);

  // ---- prologue ----
  // Q fragments (iteration-invariant): wave wid owns score rows wid*16..+15
  bf16x8 qah[2], qal[2];
  {
    const size_t qg = ((size_t)b * NN + q0 + wid * 16 + l15) * CK + lk8;
    qah[0] = *(const bf16x8*)&Qhi[qg];
    qah[1] = *(const bf16x8*)&Qhi[qg + 32];
    qal[0] = *(const bf16x8*)&Qlo[qg];
    qal[1] = *(const bf16x8*)&Qlo[qg + 32];
  }
  { // K tile 0 -> LDS (swizzled)
    const size_t g = ((size_t)b * NN + srow) * CK + sch;
    *(u32x4*)&L.kh[srow][ssw0] = *(const u32x4*)&Khi[g];
    *(u32x4*)&L.kh[srow][ssw1] = *(const u32x4*)&Khi[g + 8];
    *(u32x4*)&L.kl[srow][ssw0] = *(const u32x4*)&Klo[g];
    *(u32x4*)&L.kl[srow][ssw1] = *(const u32x4*)&Klo[g + 8];
  }
  if (tid < 64) { L.m[tid] = -__builtin_huge_valf(); L.l[tid] = 0.f; }

  // per-wave V base: rows o = ohalf*256 + wid*64 + fj*16 + l15
  const u16* vbase = Vt + ((size_t)b * CC + ohalf * 256 + wid * 64 + l15) * NN + lk8;

  f32x4 accO[4][4] = {};  // [q frag][o frag]

  __syncthreads();  // K0 + m/l init visible (full barrier ok in prologue)

  for (int t = 0; t < 64; ++t) {
    const int m0 = t * 64;
    const bool hasNext = (t < 63);

    // --- issue next-K global loads (in flight across barriers now) ---
    u32x4 kh0, kh1, kl0, kl1;
    if (hasNext) {
      const size_t g = ((size_t)b * NN + m0 + 64 + srow) * CK + sch;
      kh0 = *(const u32x4*)&Khi[g];
      kh1 = *(const u32x4*)&Khi[g + 8];
      kl0 = *(const u32x4*)&Klo[g];
      kl1 = *(const u32x4*)&Klo[g + 8];
    }
    // --- issue V fragment loads for THIS tile (consumed in PV) ---
    bf16x8 vr[2][4];  // [ks][fj]
#pragma unroll
    for (int f_ = 0; f_ < 4; ++f_)
#pragma unroll
      for (int ks = 0; ks < 2; ++ks)
        vr[ks][f_] = *(const bf16x8*)(vbase + (size_t)f_ * 16 * NN + m0 + ks * 32);

    // --- QK^T: wave wid does score rows wid*16, all 4 col frags ---
    __builtin_amdgcn_s_setprio(1);
#pragma unroll
    for (int fj = 0; fj < 4; ++fj) {
      f32x4 s = {};
#pragma unroll
      for (int ks = 0; ks < 2; ++ks) {
        const int k = ks * 32 + lk8;
        const int br = fj * 16 + l15;
        bf16x8 bh = *(const bf16x8*)&L.kh[br][k ^ ((br & 7) << 3)];
        bf16x8 bl = *(const bf16x8*)&L.kl[br][k ^ ((br & 7) << 3)];
        s = MFMA16(qah[ks], bh, s);
        s = MFMA16(qah[ks], bl, s);
        s = MFMA16(qal[ks], bh, s);
      }
      const int r0 = wid * 16 + (lane >> 4) * 4, c0 = fj * 16 + l15;
#pragma unroll
      for (int r = 0; r < 4; ++r) L.s[r0 + r][c0] = s[r];
    }
    __builtin_amdgcn_s_setprio(0);
    lds_barrier();  // barrier A: s visible; QK^T K-reads + prev p-reads done

    // --- write next K tile (single buffer: reads for t done before A) ---
    if (hasNext) {
      *(u32x4*)&L.kh[srow][ssw0] = kh0;
      *(u32x4*)&L.kh[srow][ssw1] = kh1;
      *(u32x4*)&L.kl[srow][ssw0] = kl0;
      *(u32x4*)&L.kl[srow][ssw1] = kl1;
    }
    // --- online softmax (log2 domain), defer-max: 4 threads/row ---
    {
      const int row = srow, sub = tid & 3;
      const float* sr = &L.s[row][sch];
      f32x4 a0 = *(const f32x4*)&sr[0];
      f32x4 a1 = *(const f32x4*)&sr[4];
      f32x4 a2 = *(const f32x4*)&sr[8];
      f32x4 a3 = *(const f32x4*)&sr[12];
      float mx = fmaxf(fmaxf(fmaxf(a0[0], a0[1]), fmaxf(a0[2], a0[3])),
                       fmaxf(fmaxf(a1[0], a1[1]), fmaxf(a1[2], a1[3])));
      mx = fmaxf(mx, fmaxf(fmaxf(fmaxf(a2[0], a2[1]), fmaxf(a2[2], a2[3])),
                           fmaxf(fmaxf(a3[0], a3[1]), fmaxf(a3[2], a3[3]))));
      mx = fmaxf(mx, __shfl_xor(mx, 1));
      mx = fmaxf(mx, __shfl_xor(mx, 2));
      const float mOld = L.m[row];
      const bool grow = (mx > mOld + 11.5f);  // e^8 in log2 domain (T13)
      const float mNew = grow ? mx : mOld;
      float pv[16];
      float sum = 0.f;
#pragma unroll
      for (int j = 0; j < 4; ++j) { pv[j]      = fast_exp2(a0[j] - mNew); sum += pv[j]; }
#pragma unroll
      for (int j = 0; j < 4; ++j) { pv[4 + j]  = fast_exp2(a1[j] - mNew); sum += pv[4 + j]; }
#pragma unroll
      for (int j = 0; j < 4; ++j) { pv[8 + j]  = fast_exp2(a2[j] - mNew); sum += pv[8 + j]; }
#pragma unroll
      for (int j = 0; j < 4; ++j) { pv[12 + j] = fast_exp2(a3[j] - mNew); sum += pv[12 + j]; }
      sum += __shfl_xor(sum, 1);
      sum += __shfl_xor(sum, 2);
      const float scf = grow ? fast_exp2(mOld - mNew) : 1.0f;
      if (sub == 0) {
        if (grow) L.m[row] = mNew;
        L.l[row] = L.l[row] * scf + sum;
        L.sc[row] = scf;
      }
      u16x8 pb0, pb1;
#pragma unroll
      for (int j = 0; j < 8; ++j) pb0[j] = cvt_bf16(pv[j]);
#pragma unroll
      for (int j = 0; j < 8; ++j) pb1[j] = cvt_bf16(pv[8 + j]);
      *(u16x8*)&L.p[row][ssw0] = pb0;
      *(u16x8*)&L.p[row][ssw1] = pb1;
    }
    lds_barrier();  // barrier B: p + K[t+1] + m/l/sc visible

    // --- gated rescale (usually skipped after warm-up) ---
    {
      f32x4 scv[4];
      bool need = false;
#pragma unroll
      for (int f_ = 0; f_ < 4; ++f_) {
        scv[f_] = *(const f32x4*)&L.sc[f_ * 16 + (lane >> 4) * 4];
        need |= (scv[f_][0] != 1.0f) | (scv[f_][1] != 1.0f) |
                (scv[f_][2] != 1.0f) | (scv[f_][3] != 1.0f);
      }
      if (__any(need)) {
#pragma unroll
        for (int f_ = 0; f_ < 4; ++f_)
#pragma unroll
          for (int fj = 0; fj < 4; ++fj)
#pragma unroll
            for (int r = 0; r < 4; ++r)
              accO[f_][fj][r] *= scv[f_][r];
      }
    }
    // --- PV (V operands already in regs) ---
    __builtin_amdgcn_s_setprio(1);
#pragma unroll
    for (int ks = 0; ks < 2; ++ks) {
      const int k = ks * 32 + lk8;
      bf16x8 a[4];
#pragma unroll
      for (int f_ = 0; f_ < 4; ++f_) {
        const int ar = f_ * 16 + l15;
        a[f_] = *(const bf16x8*)&L.p[ar][k ^ ((ar & 7) << 3)];
      }
#pragma unroll
      for (int fj = 0; fj < 4; ++fj)
#pragma unroll
        for (int f_ = 0; f_ < 4; ++f_)
          accO[f_][fj] = MFMA16(a[f_], vr[ks][fj], accO[f_][fj]);
    }
    __builtin_amdgcn_s_setprio(0);
  }
  __syncthreads();  // full barrier before epilogue (L.l reads)
  // epilogue: out = alpha * (O / l) + x
  const float al = alpha[0];
#pragma unroll
  for (int f_ = 0; f_ < 4; ++f_) {
    const int r0 = f_ * 16 + (lane >> 4) * 4;
    const float rl0 = 1.f / L.l[r0],     rl1 = 1.f / L.l[r0 + 1];
    const float rl2 = 1.f / L.l[r0 + 2], rl3 = 1.f / L.l[r0 + 3];
    const int n_ = q0 + r0;
#pragma unroll
    for (int fj = 0; fj < 4; ++fj) {
      const int c_ = ohalf * 256 + wid * 64 + fj * 16 + l15;
      const size_t g = ((size_t)b * CC + c_) * NN + n_;
      f32x4 xv = *(const f32x4*)&x[g];
      f32x4 ov;
      ov[0] = fmaf(al, accO[f_][fj][0] * rl0, xv[0]);
      ov[1] = fmaf(al, accO[f_][fj][1] * rl1, xv[1]);
      ov[2] = fmaf(al, accO[f_][fj][2] * rl2, xv[2]);
      ov[3] = fmaf(al, accO[f_][fj][3] * rl3, xv[3]);
      *(f32x4*)&out[g] = ov;
    }
  }
}

extern "C" void kernel_launch(void* const* d_in, const int* in_sizes, int n_in,
                              void* d_out, int out_size, void* d_ws, size_t ws_size,
                              hipStream_t stream) {
  const float* x     = (const float*)d_in[0];
  const float* wb    = (const float*)d_in[1];
  const float* bb    = (const float*)d_in[2];
  const float* wc    = (const float*)d_in[3];
  const float* bc    = (const float*)d_in[4];
  const float* wd    = (const float*)d_in[5];
  const float* bd    = (const float*)d_in[6];
  const float* alpha = (const float*)d_in[7];
  float* out = (float*)d_out;

  // workspace: Qhi|Qlo|Khi|Klo (2MB each) + Vt (16MB) = 24MB
  u16* Qhi = (u16*)d_ws;
  u16* Qlo = Qhi + (size_t)NB * NN * CK;
  u16* Khi = Qlo + (size_t)NB * NN * CK;
  u16* Klo = Khi + (size_t)NB * NN * CK;
  u16* Vt  = Klo + (size_t)NB * NN * CK;

  proj_qk<<<dim3(NN / 64, 2, NB), 256, 0, stream>>>(x, wb, bb, wc, bc, Qhi, Qlo, Khi, Klo);
  proj_v<<<dim3(NN / 64, CC / 64, NB), 256, 0, stream>>>(x, wd, bd, Vt);
  attn<<<dim3(512), 256, 0, stream>>>(Qhi, Qlo, Khi, Klo, Vt, x, alpha, out);
}